// Round 4
// baseline (447.943 us; speedup 1.0000x reference)
//
#include <hip/hip_runtime.h>

// LSTM autoencoder: 4 layers 64->64, B=512, T=256 — fused, single barrier/tick.
//
// 256 blocks x 512 threads (1 block/CU). Block = 2 batch elements x 4 layers.
// Wave w = (layer L = w>>1, unit-half mh = w&1) owns all 4 gates of units
// [mh*32, mh*32+32).
//
// TRANSPOSED MFMA (this round): compute C' = v^T * W^T instead of W * v.
// For 16x16x32, A-frag and B-frag have the same per-lane layout
// (lane&15 x (lane>>4)*8+kk), so the OLD weight fragments serve directly as
// the B operand and the OLD h/x fragments serve directly as the A operand —
// only the intrinsic argument order changes. C' rows = batch (lanes q==0,
// regs 0/1), cols = units. Each lane n<16 holds ALL 4 gates for its 2 units
// x 2 batches IN REGISTERS -> epilogue is register-local: the per-wave LDS
// gate scratch (Gs) and its scatter/gather round-trip are GONE, and cell
// state cst lives in registers of lanes q==0.
//
// Per tick tau (layer L at t = tau-L):
//   1. read h (and v = h_{L-1} | x) fragments from LDS parity (tau+1)&1
//   2. 32 MFMA (16x16x32 f16), accumulate 8 tiles (4 gates x 2 unit-blocks)
//   3. lanes q==0: register-local epilogue for 2 units x 2 batches;
//      h -> Hb[tau&1] (4x ds_write_b16); L3 stores out
//   4. raw s_barrier with lgkmcnt(0)-ONLY drain — vmcnt stays in flight
//      (x prefetch + out stores never serialize the tick).
// L0's x is prefetched one tick ahead into statically-named f32 regs.

typedef _Float16 f16x8 __attribute__((ext_vector_type(8)));
typedef float    f32x4 __attribute__((ext_vector_type(4)));

#define TSEQ 256

__device__ __forceinline__ float fast_rcp(float x) { return __builtin_amdgcn_rcpf(x); }
__device__ __forceinline__ float sigm(float x) { return fast_rcp(1.0f + __expf(-x)); }
__device__ __forceinline__ float tanh_fast(float x) {
    return 2.0f * fast_rcp(1.0f + __expf(-2.0f * x)) - 1.0f;
}
__device__ __forceinline__ f16x8 cvt8(float4 a, float4 b) {
    f16x8 f;
    f[0] = (_Float16)a.x; f[1] = (_Float16)a.y; f[2] = (_Float16)a.z; f[3] = (_Float16)a.w;
    f[4] = (_Float16)b.x; f[5] = (_Float16)b.y; f[6] = (_Float16)b.z; f[7] = (_Float16)b.w;
    return f;
}

__global__ __launch_bounds__(512, 2)
void lstm_fused7(const float* __restrict__ x,     // [512, 256, 64]
                 float* __restrict__ out,         // [512, 256, 64]
                 const float* __restrict__ Wih0, const float* __restrict__ Whh0,
                 const float* __restrict__ bi0,  const float* __restrict__ bh0,
                 const float* __restrict__ Wih1, const float* __restrict__ Whh1,
                 const float* __restrict__ bi1,  const float* __restrict__ bh1,
                 const float* __restrict__ Wih2, const float* __restrict__ Whh2,
                 const float* __restrict__ bi2,  const float* __restrict__ bh2,
                 const float* __restrict__ Wih3, const float* __restrict__ Whh3,
                 const float* __restrict__ bi3,  const float* __restrict__ bh3)
{
    __shared__ _Float16 Hb[2][4][2][64];     // 2 KB: parity, layer, el, unit

    const int tid  = threadIdx.x;
    const int wave = tid >> 6;
    const int lane = tid & 63;
    const int L    = wave >> 1;     // layer 0..3
    const int mh   = wave & 1;      // unit-half: units [mh*32, mh*32+32)
    const int q    = lane >> 4;     // k-quad
    const int n    = lane & 15;     // A rows / C cols; batch rows are 0,1
    const int b0   = blockIdx.x * 2;

    const float* Wih = (L == 0) ? Wih0 : (L == 1) ? Wih1 : (L == 2) ? Wih2 : Wih3;
    const float* Whh = (L == 0) ? Whh0 : (L == 1) ? Whh1 : (L == 2) ? Whh2 : Whh3;
    const float* bi  = (L == 0) ? bi0  : (L == 1) ? bi1  : (L == 2) ? bi2  : bi3;
    const float* bh  = (L == 0) ? bh0  : (L == 1) ? bh1  : (L == 2) ? bh2  : bh3;

    // ---- persistent W fragments, used as the MFMA *B* operand ----
    // B[k=q*8+kk][col=n] = W[row][c*32+q*8+kk], row = g*64+mh*32+s*16+n.
    // (Identical per-lane bytes as the old A-operand load.)
    f16x8 Bih[4][2][2], Bhh[4][2][2];
#pragma unroll
    for (int g = 0; g < 4; ++g) {
#pragma unroll
        for (int s = 0; s < 2; ++s) {
            const int row = g * 64 + mh * 32 + s * 16 + n;
#pragma unroll
            for (int c = 0; c < 2; ++c) {
                const float* pi = Wih + row * 64 + c * 32 + q * 8;
                const float* ph = Whh + row * 64 + c * 32 + q * 8;
                f16x8 fi, fh;
#pragma unroll
                for (int k = 0; k < 8; ++k) { fi[k] = (_Float16)pi[k]; fh[k] = (_Float16)ph[k]; }
                Bih[g][s][c] = fi;
                Bhh[g][s][c] = fh;
            }
        }
    }

    // ---- epilogue identity: lanes q==0 own units u(s)=mh*32+s*16+n, b=0,1 ----
    float be[4][2];
#pragma unroll
    for (int g = 0; g < 4; ++g)
#pragma unroll
        for (int s = 0; s < 2; ++s) {
            const int u = g * 64 + mh * 32 + s * 16 + n;
            be[g][s] = bi[u] + bh[u];
        }
    float cst[2][2] = {{0.f, 0.f}, {0.f, 0.f}};   // [s][b], regs (static idx only)
    // L==3 out pointers (lanes q==0): col base; +t*64+s*16 at store
    float* op0 = out + ((size_t)(b0 + 0) * TSEQ) * 64 + mh * 32 + n;
    float* op1 = out + ((size_t)(b0 + 1) * TSEQ) * 64 + mh * 32 + n;

    // ---- zero h state (both parities): 2048 B = 512 ints ----
    ((int*)Hb)[tid] = 0;

    // ---- L0 x prefetch: raw f32 one tick ahead (lanes n<2 only; rest zero) ----
    const float* xbase = x + ((size_t)(b0 + (n & 1)) * TSEQ) * 64 + q * 8;
    float4 R0, R1, R2, R3;
    R0 = R1 = R2 = R3 = make_float4(0.f, 0.f, 0.f, 0.f);
    if (L == 0 && n < 2) {
        R0 = *(const float4*)(xbase);      R1 = *(const float4*)(xbase + 4);
        R2 = *(const float4*)(xbase + 32); R3 = *(const float4*)(xbase + 36);
    }

    __syncthreads();

    for (int tau = 0; tau < TSEQ + 3; ++tau) {
        const int  t   = tau - L;
        const bool act = (unsigned)t < TSEQ;   // wave-uniform
        const int  pr  = (tau + 1) & 1;
        const int  pw  = tau & 1;

        if (act) {
            // ---- input fragments (A operand: rows = batch via n&1) ----
            f16x8 vf0, vf1;
            if (L == 0) {
                vf0 = cvt8(R0, R1);            // x(t)
                vf1 = cvt8(R2, R3);
                if (t + 1 < TSEQ && n < 2) {   // prefetch x(t+1)
                    const float* p = xbase + (t + 1) * 64;
                    R0 = *(const float4*)(p);      R1 = *(const float4*)(p + 4);
                    R2 = *(const float4*)(p + 32); R3 = *(const float4*)(p + 36);
                }
            } else {
                const _Float16* vp = &Hb[pr][L - 1][n & 1][0];
                vf0 = *(const f16x8*)(vp + q * 8);
                vf1 = *(const f16x8*)(vp + 32 + q * 8);
            }
            const _Float16* hp = &Hb[pr][L][n & 1][0];
            f16x8 hf0 = *(const f16x8*)(hp + q * 8);
            f16x8 hf1 = *(const f16x8*)(hp + 32 + q * 8);

            const f32x4 z4 = {0.f, 0.f, 0.f, 0.f};

            // ---- 32 MFMA, transposed: C'[batch][unit] = act * W^T ----
            f32x4 Cgs[2][4];                   // [s][g], all live to epilogue
#pragma unroll
            for (int s = 0; s < 2; ++s) {
#pragma unroll
                for (int g = 0; g < 4; ++g) {
                    f32x4 c;
                    c = __builtin_amdgcn_mfma_f32_16x16x32_f16(hf0, Bhh[g][s][0], z4, 0, 0, 0);
                    c = __builtin_amdgcn_mfma_f32_16x16x32_f16(hf1, Bhh[g][s][1], c,  0, 0, 0);
                    c = __builtin_amdgcn_mfma_f32_16x16x32_f16(vf0, Bih[g][s][0], c,  0, 0, 0);
                    Cgs[s][g] = __builtin_amdgcn_mfma_f32_16x16x32_f16(vf1, Bih[g][s][1], c, 0, 0, 0);
                }
            }

            // ---- register-local epilogue: lanes q==0, 2 units x 2 batches ----
            if (q == 0) {
#pragma unroll
                for (int s = 0; s < 2; ++s) {
                    const int u = mh * 32 + s * 16 + n;
#pragma unroll
                    for (int b = 0; b < 2; ++b) {
                        float gi = sigm(Cgs[s][0][b] + be[0][s]);
                        float gf = sigm(Cgs[s][1][b] + be[1][s]);
                        float gg = tanh_fast(Cgs[s][2][b] + be[2][s]);
                        float go = sigm(Cgs[s][3][b] + be[3][s]);
                        cst[s][b] = gf * cst[s][b] + gi * gg;
                        float h = go * tanh_fast(cst[s][b]);
                        if (L == 3) {
                            float* op = (b == 0) ? op0 : op1;
                            op[(size_t)t * 64 + s * 16] = h;
                        }
                        Hb[pw][L][b][u] = (_Float16)h;
                    }
                }
            }
        }
        // ---- raw barrier: drain LDS only; global loads/stores stay in flight ----
        __builtin_amdgcn_sched_barrier(0);
        asm volatile("s_waitcnt lgkmcnt(0)" ::: "memory");
        __builtin_amdgcn_s_barrier();
        __builtin_amdgcn_sched_barrier(0);
    }
}

extern "C" void kernel_launch(void* const* d_in, const int* in_sizes, int n_in,
                              void* d_out, int out_size, void* d_ws, size_t ws_size,
                              hipStream_t stream) {
    const float* x = (const float*)d_in[0];
    float* out = (float*)d_out;

    lstm_fused7<<<256, 512, 0, stream>>>(
        x, out,
        (const float*)d_in[1],  (const float*)d_in[2],
        (const float*)d_in[3],  (const float*)d_in[4],
        (const float*)d_in[5],  (const float*)d_in[6],
        (const float*)d_in[7],  (const float*)d_in[8],
        (const float*)d_in[9],  (const float*)d_in[10],
        (const float*)d_in[11], (const float*)d_in[12],
        (const float*)d_in[13], (const float*)d_in[14],
        (const float*)d_in[15], (const float*)d_in[16]);
}